// Round 3
// baseline (313.382 us; speedup 1.0000x reference)
//
#include <hip/hip_runtime.h>
#include <hip/hip_bf16.h>

// B=8, T=4096 -> 32768 tokens, D=1024, V=64.
// Inputs fp32: x[32768,1024], idx int32[32768], emb[64,1024], head[64,1024],
// gate[1024], soft_gate[1024].
// Output FLOAT32 (harness uses fp32 for the mixed fp32/int64 tuple):
//   x_out [32768*1024] then new_idx [32768] (as floats 0..63).
// Precision: approx logits via bf16 MFMA (err ~0.09, fine for softmax/soft_emb,
// threshold 1.26); argmax via exact fp32 recompute of approx top-4 candidates.

#define DIMS 1024
#define VOCAB 64
#define NTOK 32768
#define TTILE 16
#define TPB 256
#define IDX_OFF (NTOK * DIMS)

typedef __attribute__((ext_vector_type(8))) short short8;   // 8 x bf16
typedef __attribute__((ext_vector_type(4))) float f32x4;

__device__ __forceinline__ float sigm(float z) {
    return 1.f / (1.f + __expf(-z));
}
__device__ __forceinline__ unsigned short f2bf(float f) {
    __hip_bfloat16 h = __float2bfloat16(f);   // RTNE
    return *reinterpret_cast<unsigned short*>(&h);
}

// Pre-kernel: headB[v][d] = bf16(head[v][d]) (MFMA B for logits),
// embT[d][v] = bf16(emb[v][d]) (MFMA B for soft_emb). 128KB each in d_ws.
__global__ void prep_weights(const float* __restrict__ head,
                             const float* __restrict__ emb,
                             __hip_bfloat16* __restrict__ headB,
                             __hip_bfloat16* __restrict__ embT) {
    int t = blockIdx.x * 256 + threadIdx.x;   // 0..65535 = v*1024+d
    int v = t >> 10, d = t & 1023;
    headB[t] = __float2bfloat16(head[t]);
    embT[d * VOCAB + v] = __float2bfloat16(emb[v * DIMS + d]);
}

__global__ __launch_bounds__(TPB, 2) void fused_block(
    const float* __restrict__ x,
    const int* __restrict__ idx,
    const float* __restrict__ emb,
    const float* __restrict__ gate,
    const float* __restrict__ sgate,
    const float* __restrict__ headF,          // fp32 head (exact recompute)
    const __hip_bfloat16* __restrict__ headB, // bf16 head
    const __hip_bfloat16* __restrict__ embT,  // bf16 emb^T
    float* __restrict__ out)
{
    // bf16 x1 tile for MFMA A-frags; row stride 1032 (2064B) rotates banks.
    __shared__ __align__(16) __hip_bfloat16 sX1b[TTILE][1032];  // 33024 B
    __shared__ __align__(16) float          sLog[TTILE][68];    //  4352 B
    __shared__ __align__(16) __hip_bfloat16 sP[TTILE][72];      //  2304 B
    __shared__ float sSg[TTILE];
    __shared__ int   sCand[TTILE][4];

    const int tid  = threadIdx.x;
    const int tk   = tid >> 4;        // token-in-tile 0..15
    const int l16i = tid & 15;        // 16 threads per token
    const long t0  = (long)blockIdx.x * TTILE;
    const long tok = t0 + tk;

    // ---------- Phase A: load x row, g-blend with emb[idx], sg; x1 -> regs (fp32) + LDS (bf16) ----------
    float4 xv[16];                    // x, then overwritten with x1; d = 4*l16i + 64*c .. +3
    float gsum = 0.f;
    const float4* xrow = (const float4*)(x + tok * DIMS);
    const float4* grow = (const float4*)gate;
    #pragma unroll
    for (int c = 0; c < 16; c++) {
        int f = l16i + c * 16;
        float4 v = xrow[f];
        float4 gv = grow[f];
        xv[c] = v;
        gsum += sigm(v.x * gv.x) + sigm(v.y * gv.y)
              + sigm(v.z * gv.z) + sigm(v.w * gv.w);
    }
    gsum += __shfl_xor(gsum, 1); gsum += __shfl_xor(gsum, 2);
    gsum += __shfl_xor(gsum, 4); gsum += __shfl_xor(gsum, 8);
    const float g = gsum * (1.f / 1024.f);

    int ic = idx[tok]; if (ic < 0) ic = 0;            // jnp.clip(idx, 0, None)
    const float4* erow = (const float4*)(emb + (long)ic * DIMS);
    const float4* srow = (const float4*)sgate;
    float ssum = 0.f;
    #pragma unroll
    for (int c = 0; c < 16; c++) {
        int f = l16i + c * 16;
        float4 ev = erow[f];
        float4 sv = srow[f];
        float4 a;
        a.x = xv[c].x * (1.f - g) + ev.x * g;
        a.y = xv[c].y * (1.f - g) + ev.y * g;
        a.z = xv[c].z * (1.f - g) + ev.z * g;
        a.w = xv[c].w * (1.f - g) + ev.w * g;
        xv[c] = a;                                    // keep exact x1 in regs
        ssum += sigm(a.x * sv.x) + sigm(a.y * sv.y)
              + sigm(a.z * sv.z) + sigm(a.w * sv.w);
        ushort4 pk;
        pk.x = f2bf(a.x); pk.y = f2bf(a.y); pk.z = f2bf(a.z); pk.w = f2bf(a.w);
        *(ushort4*)&sX1b[tk][f * 4] = pk;             // 8B aligned write
    }
    ssum += __shfl_xor(ssum, 1); ssum += __shfl_xor(ssum, 2);
    ssum += __shfl_xor(ssum, 4); ssum += __shfl_xor(ssum, 8);
    if (l16i == 0) sSg[tk] = ssum * (1.f / 1024.f);
    __syncthreads();

    // ---------- Phase B: approx logits[16][64] = x1.head^T via bf16 MFMA ----------
    const int w    = tid >> 6;        // wave 0..3 -> vocab n-tile
    const int lane = tid & 63;
    const int quad = lane >> 4, l16 = lane & 15;
    {
        f32x4 acc = {0.f, 0.f, 0.f, 0.f};
        const __hip_bfloat16* hrow = headB + (long)(w * 16 + l16) * DIMS + quad * 8;
        #pragma unroll 4
        for (int k0 = 0; k0 < DIMS; k0 += 32) {
            short8 a = *(const short8*)&sX1b[l16][k0 + quad * 8];
            short8 b = *(const short8*)(hrow + k0);
            acc = __builtin_amdgcn_mfma_f32_16x16x32_bf16(a, b, acc, 0, 0, 0);
        }
        #pragma unroll
        for (int i = 0; i < 4; i++)
            sLog[quad * 4 + i][w * 16 + l16] = acc[i];   // D: row(token)=quad*4+i, col=lane&15
    }
    __syncthreads();

    // ---------- Phase C: softmax over 64 + approx top-4, one wave per token ----------
    #pragma unroll
    for (int it = 0; it < 4; it++) {
        int m = it * 4 + w;
        float l0 = sLog[m][lane];
        float mx = l0;
        mx = fmaxf(mx, __shfl_xor(mx, 1));  mx = fmaxf(mx, __shfl_xor(mx, 2));
        mx = fmaxf(mx, __shfl_xor(mx, 4));  mx = fmaxf(mx, __shfl_xor(mx, 8));
        mx = fmaxf(mx, __shfl_xor(mx, 16)); mx = fmaxf(mx, __shfl_xor(mx, 32));
        float e = __expf(l0 - mx);
        float s = e;
        s += __shfl_xor(s, 1);  s += __shfl_xor(s, 2);  s += __shfl_xor(s, 4);
        s += __shfl_xor(s, 8);  s += __shfl_xor(s, 16); s += __shfl_xor(s, 32);
        sP[m][lane] = __float2bfloat16(e / s);
        // top-4 by approx logit (descending), distinct indices
        float l = l0;
        int c0i, c1i, c2i, c3i;
        {
            float mj = l;
            mj = fmaxf(mj, __shfl_xor(mj, 1));  mj = fmaxf(mj, __shfl_xor(mj, 2));
            mj = fmaxf(mj, __shfl_xor(mj, 4));  mj = fmaxf(mj, __shfl_xor(mj, 8));
            mj = fmaxf(mj, __shfl_xor(mj, 16)); mj = fmaxf(mj, __shfl_xor(mj, 32));
            c0i = __ffsll(__ballot(l == mj)) - 1; if (lane == c0i) l = -3.4e38f;
        }
        {
            float mj = l;
            mj = fmaxf(mj, __shfl_xor(mj, 1));  mj = fmaxf(mj, __shfl_xor(mj, 2));
            mj = fmaxf(mj, __shfl_xor(mj, 4));  mj = fmaxf(mj, __shfl_xor(mj, 8));
            mj = fmaxf(mj, __shfl_xor(mj, 16)); mj = fmaxf(mj, __shfl_xor(mj, 32));
            c1i = __ffsll(__ballot(l == mj)) - 1; if (lane == c1i) l = -3.4e38f;
        }
        {
            float mj = l;
            mj = fmaxf(mj, __shfl_xor(mj, 1));  mj = fmaxf(mj, __shfl_xor(mj, 2));
            mj = fmaxf(mj, __shfl_xor(mj, 4));  mj = fmaxf(mj, __shfl_xor(mj, 8));
            mj = fmaxf(mj, __shfl_xor(mj, 16)); mj = fmaxf(mj, __shfl_xor(mj, 32));
            c2i = __ffsll(__ballot(l == mj)) - 1; if (lane == c2i) l = -3.4e38f;
        }
        {
            float mj = l;
            mj = fmaxf(mj, __shfl_xor(mj, 1));  mj = fmaxf(mj, __shfl_xor(mj, 2));
            mj = fmaxf(mj, __shfl_xor(mj, 4));  mj = fmaxf(mj, __shfl_xor(mj, 8));
            mj = fmaxf(mj, __shfl_xor(mj, 16)); mj = fmaxf(mj, __shfl_xor(mj, 32));
            c3i = __ffsll(__ballot(l == mj)) - 1;
        }
        if (lane == 0) {
            sCand[m][0] = c0i; sCand[m][1] = c1i;
            sCand[m][2] = c2i; sCand[m][3] = c3i;
        }
    }
    __syncthreads();

    // ---------- Phase C'': exact fp32 logits for the 4 candidates; argmax ----------
    // thread (tk,l16i) holds x1 at d = 4*l16i + 64*c in xv[c]. head rows from
    // global fp32 (L2-resident). 16-lane coalesced 256B segments.
    {
        int rows[4];
        #pragma unroll
        for (int j = 0; j < 4; j++) rows[j] = sCand[tk][j];
        float tot[4];
        #pragma unroll
        for (int j = 0; j < 4; j++) {
            const float4* hr = (const float4*)(headF + (long)rows[j] * DIMS);
            float p = 0.f;
            #pragma unroll
            for (int c = 0; c < 16; c++) {
                float4 h = hr[l16i + c * 16];
                p = fmaf(xv[c].x, h.x, p); p = fmaf(xv[c].y, h.y, p);
                p = fmaf(xv[c].z, h.z, p); p = fmaf(xv[c].w, h.w, p);
            }
            p += __shfl_xor(p, 1); p += __shfl_xor(p, 2);
            p += __shfl_xor(p, 4); p += __shfl_xor(p, 8);
            tot[j] = p;
        }
        if (l16i == 0) {
            float bv = tot[0]; int bi = rows[0];
            #pragma unroll
            for (int j = 1; j < 4; j++) {
                if (tot[j] > bv || (tot[j] == bv && rows[j] < bi)) {
                    bv = tot[j]; bi = rows[j];
                }
            }
            out[IDX_OFF + tok] = (float)bi;     // np.argmax: ties -> lowest index
        }
    }

    // ---------- Phase D: soft_emb = P.emb via bf16 MFMA + blend + fp32 store ----------
    #pragma unroll 1
    for (int i = 0; i < 16; i++) {
        int n0 = (i * 4 + w) * 16;              // wave-disjoint n-tiles
        f32x4 acc = {0.f, 0.f, 0.f, 0.f};
        #pragma unroll
        for (int k0 = 0; k0 < VOCAB; k0 += 32) {
            short8 a = *(const short8*)&sP[l16][k0 + quad * 8];
            short8 b = *(const short8*)(embT + (long)(n0 + l16) * VOCAB + k0 + quad * 8);
            acc = __builtin_amdgcn_mfma_f32_16x16x32_bf16(a, b, acc, 0, 0, 0);
        }
        #pragma unroll
        for (int r = 0; r < 4; r++) {
            int m = quad * 4 + r;               // D: row=quad*4+r, col=lane&15
            int n = n0 + l16;
            float sg = sSg[m];
            float x1f = __bfloat162float(sX1b[m][n]);
            out[(t0 + m) * (long)DIMS + n] = x1f * (1.f - sg) + acc[r] * sg;
        }
    }
}

extern "C" void kernel_launch(void* const* d_in, const int* in_sizes, int n_in,
                              void* d_out, int out_size, void* d_ws, size_t ws_size,
                              hipStream_t stream) {
    const float* xp    = (const float*)d_in[0];
    const int*   idxp  = (const int*)d_in[1];
    const float* embp  = (const float*)d_in[2];
    const float* headp = (const float*)d_in[3];
    const float* gp    = (const float*)d_in[4];
    const float* sgp   = (const float*)d_in[5];
    float*       outp  = (float*)d_out;

    __hip_bfloat16* headB = (__hip_bfloat16*)d_ws;                        // 128 KB
    __hip_bfloat16* embT  = (__hip_bfloat16*)((char*)d_ws + 131072);      // 128 KB

    prep_weights<<<dim3(256), dim3(256), 0, stream>>>(headp, embp, headB, embT);
    fused_block<<<dim3(NTOK / TTILE), dim3(TPB), 0, stream>>>(
        xp, idxp, embp, gp, sgp, headp, headB, embT, outp);
}

// Round 4
// 309.150 us; speedup vs baseline: 1.0137x; 1.0137x over previous
//
#include <hip/hip_runtime.h>
#include <hip/hip_bf16.h>

// B=8, T=4096 -> 32768 tokens, D=1024, V=64.
// Inputs fp32: x[32768,1024], idx int32[32768], emb[64,1024], head[64,1024],
// gate[1024], soft_gate[1024].
// Output fp32: x_out [32768*1024] then new_idx [32768] (floats 0..63).
// Algorithm (validated R3): approx logits via bf16 MFMA -> softmax/soft_emb;
// argmax via exact fp32 recompute of approx top-4 candidates.
// R4 restructure: 512 thr/block, 32 lanes/token -> xv[8] (32 VGPR, no spill).

#define DIMS 1024
#define VOCAB 64
#define NTOK 32768
#define TTILE 16
#define TPB 512
#define IDX_OFF (NTOK * DIMS)

typedef __attribute__((ext_vector_type(8))) short short8;   // 8 x bf16
typedef __attribute__((ext_vector_type(4))) float f32x4;

__device__ __forceinline__ float sigm(float z) {
    return 1.f / (1.f + __expf(-z));
}
__device__ __forceinline__ unsigned short f2bf(float f) {
    __hip_bfloat16 h = __float2bfloat16(f);   // RTNE
    return *reinterpret_cast<unsigned short*>(&h);
}

// headB[v][d]=bf16(head), embT[d][v]=bf16(emb^T). 128KB each in d_ws.
__global__ void prep_weights(const float* __restrict__ head,
                             const float* __restrict__ emb,
                             __hip_bfloat16* __restrict__ headB,
                             __hip_bfloat16* __restrict__ embT) {
    int t = blockIdx.x * 256 + threadIdx.x;   // v*1024+d
    int v = t >> 10, d = t & 1023;
    headB[t] = __float2bfloat16(head[t]);
    embT[d * VOCAB + v] = __float2bfloat16(emb[v * DIMS + d]);
}

__global__ __launch_bounds__(TPB, 6) void fused_block(
    const float* __restrict__ x,
    const int* __restrict__ idx,
    const float* __restrict__ emb,
    const float* __restrict__ gate,
    const float* __restrict__ sgate,
    const float* __restrict__ headF,          // fp32 head (exact recompute)
    const __hip_bfloat16* __restrict__ headB,
    const __hip_bfloat16* __restrict__ embT,
    float* __restrict__ out)
{
    __shared__ __align__(16) __hip_bfloat16 sX1b[TTILE][1032];   // 33024 B
    __shared__ __align__(16) float          sLogP[2][TTILE][68]; //  8704 B (K-half partials)
    __shared__ __align__(16) __hip_bfloat16 sP[TTILE][72];       //  2304 B
    __shared__ float sSg[TTILE];                                 // total ~44 KB -> 3 blk/CU

    const int tid  = threadIdx.x;
    const int tk   = tid >> 5;        // token-in-tile 0..15 (32 lanes each)
    const int l32  = tid & 31;
    const long t0  = (long)blockIdx.x * TTILE;
    const long tok = t0 + tk;

    // ---------- Phase A: load x, g-blend with emb[idx], sg; x1 -> regs(fp32) + LDS(bf16) ----------
    float4 xv[8];                     // x1 at d = 4*(l32 + c*32) .. +3
    float gsum = 0.f;
    const float4* xrow = (const float4*)(x + tok * DIMS);
    const float4* grow = (const float4*)gate;
    #pragma unroll
    for (int c = 0; c < 8; c++) {
        int f = l32 + c * 32;
        float4 v = xrow[f];
        float4 gv = grow[f];
        xv[c] = v;
        gsum += sigm(v.x * gv.x) + sigm(v.y * gv.y)
              + sigm(v.z * gv.z) + sigm(v.w * gv.w);
    }
    gsum += __shfl_xor(gsum, 1); gsum += __shfl_xor(gsum, 2);
    gsum += __shfl_xor(gsum, 4); gsum += __shfl_xor(gsum, 8);
    gsum += __shfl_xor(gsum, 16);
    const float g = gsum * (1.f / 1024.f);

    int ic = idx[tok]; if (ic < 0) ic = 0;            // jnp.clip(idx, 0, None)
    const float4* erow = (const float4*)(emb + (long)ic * DIMS);
    const float4* srow = (const float4*)sgate;
    float ssum = 0.f;
    #pragma unroll
    for (int c = 0; c < 8; c++) {
        int f = l32 + c * 32;
        float4 ev = erow[f];
        float4 sv = srow[f];
        float4 a;
        a.x = xv[c].x * (1.f - g) + ev.x * g;
        a.y = xv[c].y * (1.f - g) + ev.y * g;
        a.z = xv[c].z * (1.f - g) + ev.z * g;
        a.w = xv[c].w * (1.f - g) + ev.w * g;
        xv[c] = a;                                    // exact fp32 x1 stays in regs
        ssum += sigm(a.x * sv.x) + sigm(a.y * sv.y)
              + sigm(a.z * sv.z) + sigm(a.w * sv.w);
        ushort4 pk;
        pk.x = f2bf(a.x); pk.y = f2bf(a.y); pk.z = f2bf(a.z); pk.w = f2bf(a.w);
        *(ushort4*)&sX1b[tk][f * 4] = pk;
    }
    ssum += __shfl_xor(ssum, 1); ssum += __shfl_xor(ssum, 2);
    ssum += __shfl_xor(ssum, 4); ssum += __shfl_xor(ssum, 8);
    ssum += __shfl_xor(ssum, 16);
    if (l32 == 0) sSg[tk] = ssum * (1.f / 1024.f);
    __syncthreads();

    // ---------- Phase B: approx logits = x1.head^T via bf16 MFMA, K split over wave pairs ----------
    const int w    = tid >> 6;        // wave 0..7
    const int lane = tid & 63;
    const int quad = lane >> 4, l16 = lane & 15;
    const int nt   = w & 3;           // vocab n-tile
    const int kh   = w >> 2;          // K half (512)
    {
        f32x4 acc = {0.f, 0.f, 0.f, 0.f};
        const __hip_bfloat16* hrow = headB + (long)(nt * 16 + l16) * DIMS + kh * 512 + quad * 8;
        #pragma unroll 4
        for (int k0 = 0; k0 < 512; k0 += 32) {
            short8 a = *(const short8*)&sX1b[l16][kh * 512 + k0 + quad * 8];
            short8 b = *(const short8*)(hrow + k0);
            acc = __builtin_amdgcn_mfma_f32_16x16x32_bf16(a, b, acc, 0, 0, 0);
        }
        #pragma unroll
        for (int i = 0; i < 4; i++)
            sLogP[kh][quad * 4 + i][nt * 16 + l16] = acc[i];  // D: row=quad*4+i, col=l16
    }
    __syncthreads();

    // ---------- Phase C: softmax + approx top-4 (wave w owns tokens 2w, 2w+1) ----------
    int cA[4], cB[4];
    #pragma unroll
    for (int it = 0; it < 2; it++) {
        int m = 2 * w + it;
        float l0 = sLogP[0][m][lane] + sLogP[1][m][lane];
        float mx = l0;
        mx = fmaxf(mx, __shfl_xor(mx, 1));  mx = fmaxf(mx, __shfl_xor(mx, 2));
        mx = fmaxf(mx, __shfl_xor(mx, 4));  mx = fmaxf(mx, __shfl_xor(mx, 8));
        mx = fmaxf(mx, __shfl_xor(mx, 16)); mx = fmaxf(mx, __shfl_xor(mx, 32));
        float e = __expf(l0 - mx);
        float s = e;
        s += __shfl_xor(s, 1);  s += __shfl_xor(s, 2);  s += __shfl_xor(s, 4);
        s += __shfl_xor(s, 8);  s += __shfl_xor(s, 16); s += __shfl_xor(s, 32);
        sP[m][lane] = __float2bfloat16(e / s);
        float l = l0;
        #pragma unroll
        for (int j = 0; j < 4; j++) {
            float mj = l;
            mj = fmaxf(mj, __shfl_xor(mj, 1));  mj = fmaxf(mj, __shfl_xor(mj, 2));
            mj = fmaxf(mj, __shfl_xor(mj, 4));  mj = fmaxf(mj, __shfl_xor(mj, 8));
            mj = fmaxf(mj, __shfl_xor(mj, 16)); mj = fmaxf(mj, __shfl_xor(mj, 32));
            int cj = __ffsll(__ballot(l == mj)) - 1;   // all lanes agree
            if (lane == cj) l = -3.4e38f;
            if (it == 0) cA[j] = cj; else cB[j] = cj;
        }
    }

    // ---------- Phase C'': exact fp32 logits for 4 candidates; argmax (half-wave per token) ----------
    {
        const int h = (lane >> 5) & 1;           // half h owns token tk = 2w+h
        int rows[4];
        #pragma unroll
        for (int j = 0; j < 4; j++) rows[j] = h ? cB[j] : cA[j];
        float tot[4];
        #pragma unroll
        for (int j = 0; j < 4; j++) {
            const float4* hr = (const float4*)(headF + (long)rows[j] * DIMS);
            float p = 0.f;
            #pragma unroll
            for (int c = 0; c < 8; c++) {
                float4 hv = hr[l32 + c * 32];
                p = fmaf(xv[c].x, hv.x, p); p = fmaf(xv[c].y, hv.y, p);
                p = fmaf(xv[c].z, hv.z, p); p = fmaf(xv[c].w, hv.w, p);
            }
            p += __shfl_xor(p, 1); p += __shfl_xor(p, 2);
            p += __shfl_xor(p, 4); p += __shfl_xor(p, 8);
            p += __shfl_xor(p, 16);                   // reduce within 32-lane half
            tot[j] = p;
        }
        if (l32 == 0) {
            float bv = tot[0]; int bi = rows[0];
            #pragma unroll
            for (int j = 1; j < 4; j++) {
                if (tot[j] > bv || (tot[j] == bv && rows[j] < bi)) {
                    bv = tot[j]; bi = rows[j];
                }
            }
            out[IDX_OFF + tok] = (float)bi;           // np.argmax ties -> lowest index
        }
    }
    __syncthreads();

    // ---------- Phase D: soft_emb = P.emb via bf16 MFMA + blend + fp32 store ----------
    #pragma unroll 1
    for (int i = 0; i < 8; i++) {
        int n0 = (i * 8 + w) * 16;                    // 64 wave-disjoint n-tiles
        f32x4 acc = {0.f, 0.f, 0.f, 0.f};
        #pragma unroll
        for (int k0 = 0; k0 < VOCAB; k0 += 32) {
            short8 a = *(const short8*)&sP[l16][k0 + quad * 8];
            short8 b = *(const short8*)(embT + (long)(n0 + l16) * VOCAB + k0 + quad * 8);
            acc = __builtin_amdgcn_mfma_f32_16x16x32_bf16(a, b, acc, 0, 0, 0);
        }
        #pragma unroll
        for (int r = 0; r < 4; r++) {
            int m = quad * 4 + r;                     // D: row=quad*4+r, col=l16
            int n = n0 + l16;
            float sg = sSg[m];
            float x1f = __bfloat162float(sX1b[m][n]);
            out[(t0 + m) * (long)DIMS + n] = x1f * (1.f - sg) + acc[r] * sg;
        }
    }
}

extern "C" void kernel_launch(void* const* d_in, const int* in_sizes, int n_in,
                              void* d_out, int out_size, void* d_ws, size_t ws_size,
                              hipStream_t stream) {
    const float* xp    = (const float*)d_in[0];
    const int*   idxp  = (const int*)d_in[1];
    const float* embp  = (const float*)d_in[2];
    const float* headp = (const float*)d_in[3];
    const float* gp    = (const float*)d_in[4];
    const float* sgp   = (const float*)d_in[5];
    float*       outp  = (float*)d_out;

    __hip_bfloat16* headB = (__hip_bfloat16*)d_ws;                        // 128 KB
    __hip_bfloat16* embT  = (__hip_bfloat16*)((char*)d_ws + 131072);      // 128 KB

    prep_weights<<<dim3(256), dim3(256), 0, stream>>>(headp, embp, headB, embT);
    fused_block<<<dim3(NTOK / TTILE), dim3(TPB), 0, stream>>>(
        xp, idxp, embp, gp, sgp, headp, headB, embT, outp);
}